// Round 8
// baseline (417.661 us; speedup 1.0000x reference)
//
#include <hip/hip_runtime.h>
#include <hip/hip_bf16.h>

// Problem constants
#define BB 4
#define CC 768
#define CT 192
#define TT 2048
#define SS 1024
#define KK 12

typedef __attribute__((ext_vector_type(8))) short bfrag8;  // 8 bf16 = 4 VGPR
typedef __attribute__((ext_vector_type(4))) float f32x4;

// ---------------------------------------------------------------------------
// Fragment-layout convention (16x16x32 bf16 MFMA):
//   A: row m = lane&15, k-slot = 32*cc + (lane>>4)*8 + j
//   B: col n = lane&15, k-slot = 32*cc + (lane>>4)*8 + j
//   D: col n = lane&15, row m = (lane>>4)*4 + reg   (HW-verified)
// A/B use the SAME slot->k map so the contraction is exact.
// ---------------------------------------------------------------------------

__device__ inline unsigned pk2(float a, float b) {
    __hip_bfloat162 h2;
    h2.x = __float2bfloat16(a);
    h2.y = __float2bfloat16(b);
    return *reinterpret_cast<unsigned*>(&h2);
}

// Pack text (fp32 [b][ct][s]) into B-fragment layouts (bf16):
//  textS [b][st:64][cc:6][l:64][j:8]   (score GEMM: K=ct, N=s)
//  textC [b][ctt:12][scg:32][l:64][j:8] (context GEMM: K=s, N=ct)
__global__ void k_pack_text(const float* __restrict__ text,
                            __hip_bfloat16* __restrict__ textS,
                            __hip_bfloat16* __restrict__ textC) {
    const int b = blockIdx.x;
    const float* tb = text + (size_t)b * CT * SS;
    const int stride = blockDim.x * gridDim.y;
    const int base = threadIdx.x + blockIdx.y * blockDim.x;
    for (int e = base; e < 64 * 6 * 512; e += stride) {
        int jj = e & 7, l = (e >> 3) & 63, cc = (e >> 9) % 6, st = e / 3072;
        int ct = cc * 32 + ((l >> 4) << 3) + jj;
        int s = st * 16 + (l & 15);
        textS[(size_t)b * 196608 + e] = __float2bfloat16(tb[(size_t)ct * SS + s]);
    }
    for (int e = base; e < 12 * 32 * 512; e += stride) {
        int jj = e & 7, l = (e >> 3) & 63, scg = (e >> 9) & 31, ctt = e / 16384;
        int ct = ctt * 16 + (l & 15);
        int s = scg * 32 + ((l >> 4) << 3) + jj;
        textC[(size_t)b * 196608 + e] = __float2bfloat16(tb[(size_t)ct * SS + s]);
    }
}

// Pack y (fp32 [b][o][t]) into A-frag layout yP[b][tt:128][oc:24][l:64][j:8]
__global__ void k_pack_y(const float* __restrict__ y,
                         __hip_bfloat16* __restrict__ yP) {
    const int b = blockIdx.x;
    const float* yb_ = y + (size_t)b * CC * TT;
    const int stride = blockDim.x * gridDim.y;
    for (int e = threadIdx.x + blockIdx.y * blockDim.x; e < 128 * 24 * 512;
         e += stride) {
        int j = e & 7, l = (e >> 3) & 63, oc = (e >> 9) % 24, tt = e / 12288;
        int t = tt * 16 + (l & 15);
        int o = oc * 32 + ((l >> 4) << 3) + j;
        yP[(size_t)b * 1572864 + e] = __float2bfloat16(yb_[(size_t)o * TT + t]);
    }
}

// Pack W (fp32 [k][o][ct]) into B-frag layout WP[k][nt:12][oc:24][l:64][j:8]
__global__ void k_pack_w(const float* __restrict__ W,
                         __hip_bfloat16* __restrict__ WP) {
    const int k = blockIdx.x;
    const float* wk = W + (size_t)k * CC * CT;
    const int stride = blockDim.x * gridDim.y;
    for (int e = threadIdx.x + blockIdx.y * blockDim.x; e < 12 * 24 * 512;
         e += stride) {
        int j = e & 7, l = (e >> 3) & 63, oc = (e >> 9) % 24, nt = e / 12288;
        int ct = nt * 16 + (l & 15);
        int o = oc * 32 + ((l >> 4) << 3) + j;
        WP[(size_t)k * 147456 + e] = __float2bfloat16(wk[(size_t)o * CT + ct]);
    }
}

// ---------------------------------------------------------------------------
// yW via MFMA. 1536 blocks, XCD-swizzled: XCD x handles b = x&3 only.
// ---------------------------------------------------------------------------
__global__ __launch_bounds__(256, 2) void k_yw_mfma(
    const __hip_bfloat16* __restrict__ yP, const __hip_bfloat16* __restrict__ WP,
    __hip_bfloat16* __restrict__ ywA) {
    const int i = blockIdx.x;
    const int x = i & 7, j = i >> 3;
    const int b = x & 3;
    const int k = j >> 4;
    const int tx = (j & 15) | ((x >> 2) << 4);
    const int kb = k * BB + b;

    const int tid = threadIdx.x;
    const int w = tid >> 6, l = tid & 63;
    const int l15 = l & 15, lg = l >> 4;
    const int ttg = tx * 4 + w;

    const short* yp = reinterpret_cast<const short*>(yP) +
                      (((size_t)b * 128 + ttg) * 24) * 512 + (size_t)l * 8;
    const short* wp = reinterpret_cast<const short*>(WP) +
                      (size_t)k * 147456 + (size_t)l * 8;

    f32x4 acc[12];
#pragma unroll
    for (int nt = 0; nt < 12; ++nt) acc[nt] = (f32x4){0.f, 0.f, 0.f, 0.f};

    for (int oc = 0; oc < 24; ++oc) {
        bfrag8 af = *reinterpret_cast<const bfrag8*>(yp + oc * 512);
#pragma unroll
        for (int nt = 0; nt < 12; ++nt) {
            bfrag8 bf =
                *reinterpret_cast<const bfrag8*>(wp + (nt * 24 + oc) * 512);
            acc[nt] =
                __builtin_amdgcn_mfma_f32_16x16x32_bf16(af, bf, acc[nt], 0, 0, 0);
        }
    }

    const size_t obase = ((size_t)kb * 128 + ttg) * 3072;  // 6*512
#pragma unroll
    for (int nt = 0; nt < 12; ++nt) {
#pragma unroll
        for (int r = 0; r < 4; ++r) {
            const int ct = nt * 16 + l15;
            const int lane2 = (lg * 4 + r) | (((ct >> 3) & 3) << 4);
            ywA[obase + (size_t)(ct >> 5) * 512 + lane2 * 8 + (ct & 7)] =
                __float2bfloat16(acc[nt][r]);
        }
    }
}

// ---------------------------------------------------------------------------
// yb[k,b,t] for all 12 k in one pass over y.
// ---------------------------------------------------------------------------
__global__ __launch_bounds__(256) void k_yb2(const float* __restrict__ y,
                                             const float* __restrict__ bias,
                                             float* __restrict__ yb) {
    const int b = blockIdx.y;
    const int t0 = blockIdx.x * 64;
    const int tid = threadIdx.x;
    const int tl = tid & 63, g = tid >> 6;

    __shared__ float bs[KK][CC];
    __shared__ float pb[4][64][KK];
    for (int i = tid; i < KK * CC; i += 256) bs[i / CC][i % CC] = bias[i];
    __syncthreads();

    float p[KK];
#pragma unroll
    for (int k = 0; k < KK; ++k) p[k] = 0.f;
    const float* yb_ = y + (size_t)b * CC * TT + t0 + tl;
    for (int o = g * 192; o < g * 192 + 192; ++o) {
        float v = yb_[(size_t)o * TT];
#pragma unroll
        for (int k = 0; k < KK; ++k) p[k] += v * bs[k][o];
    }
#pragma unroll
    for (int k = 0; k < KK; ++k) pb[g][tl][k] = p[k];
    __syncthreads();
    for (int i = tid; i < 64 * KK; i += 256) {
        int tt = i / KK, k = i % KK;
        float s = pb[0][tt][k] + pb[1][tt][k] + pb[2][tt][k] + pb[3][tt][k];
        yb[((size_t)k * BB + b) * TT + t0 + tt] = s;
    }
}

// ---------------------------------------------------------------------------
// FUSED attn. R8 change: force the register-allocation occupancy target to
// 2 waves/EU so the compiler may use up to 256 VGPRs (R7's spill cost
// ~290 MB of HBM scratch traffic at the LDS-derived 128-VGPR cap):
//   (a) amdgpu_waves_per_eu(1,2) caps target occupancy explicitly;
//   (b) LDS over-declared to 128 KB (slice 0 used) so even the LDS-derived
//       default occupancy is 1 WG/CU = 2 waves/EU.
// Live set ~160 VGPR: accv[2][8]=64 + accsum[8]=32 + af pair 8 + masks/addr.
//
// 512 threads = 8 waves; wave w owns s in [w*128,(w+1)*128).
// lds_acc[w][st][l][r] (written ONCE after the head loop) holds sum_k prob
// for s = w*128+st*16+(l&15), t = t0 + (l>>4)*4 + r.
// lred double-buffered by kp-parity -> single barrier per head-pair.
// ---------------------------------------------------------------------------
__global__ __launch_bounds__(512)
__attribute__((amdgpu_waves_per_eu(1, 2))) void k_attn_fused(
    const float* __restrict__ ymask, const float* __restrict__ tmask,
    const float* __restrict__ scale, const __hip_bfloat16* __restrict__ ywA,
    const float* __restrict__ ybws, const __hip_bfloat16* __restrict__ textS,
    const __hip_bfloat16* __restrict__ textC, const float* __restrict__ y,
    const float* __restrict__ ge, float* __restrict__ out) {
    const int i = blockIdx.x;
    const int x = i & 7;
    const int b = x & 3;
    const int tt = (i >> 3) + ((x >> 2) << 6);
    const int t0 = tt * 16;
    const int tid = threadIdx.x;
    const int w = tid >> 6;       // 0..7
    const int l = tid & 63;
    const int l15 = l & 15, lg = l >> 4;
    const int ws0 = w * 128;

    // 128 KB declared; only slice [0] used. Forces 1 WG/CU occupancy calc.
    __shared__ float lds_acc_raw[2][8][8][64][4];
    float(&lds_acc)[8][8][64][4] = lds_acc_raw[0];
    __shared__ float yb_s[KK][16];
    __shared__ float sc_s[KK];
    __shared__ __align__(16) float lred[2][2][16][8];  // [kp&1][p][row][w]

    if (tid < 192)
        yb_s[tid >> 4][tid & 15] =
            ybws[(size_t)((tid >> 4) * BB + b) * TT + t0 + (tid & 15)];
    if (tid < KK) sc_s[tid] = scale[tid];
    __syncthreads();

    float tm2r[8];
#pragma unroll
    for (int st = 0; st < 8; ++st) {
        float m = tmask[b * SS + ws0 + st * 16 + l15];
        tm2r[st] = m * m;
    }
    float ymr[4];
#pragma unroll
    for (int r = 0; r < 4; ++r) ymr[r] = ymask[b * TT + t0 + lg * 4 + r];
    const float invs = 0.03608439182435161f;  // 1/sqrt(768)

    f32x4 accsum[8];
#pragma unroll
    for (int st = 0; st < 8; ++st) accsum[st] = (f32x4){0.f, 0.f, 0.f, 0.f};

    const short* ywAs = reinterpret_cast<const short*>(ywA);
    const short* tS = reinterpret_cast<const short*>(textS);
    const short* tSw = tS + (((size_t)b * 64 + w * 8) * 6) * 512 + (size_t)l * 8;
    const size_t headStride = (size_t)BB * 128 * 3072;  // shorts per head in ywA

    for (int kp = 0; kp < 6; ++kp) {
        f32x4 accv[2][8];
#pragma unroll
        for (int p = 0; p < 2; ++p)
#pragma unroll
            for (int st = 0; st < 8; ++st)
                accv[p][st] = (f32x4){0.f, 0.f, 0.f, 0.f};

        const size_t ab0 =
            (((size_t)(2 * kp * BB + b) * 128 + tt) * 6) * 512 + (size_t)l * 8;
#pragma unroll
        for (int cc = 0; cc < 6; ++cc) {
            bfrag8 af0 =
                *reinterpret_cast<const bfrag8*>(ywAs + ab0 + cc * 512);
            bfrag8 af1 = *reinterpret_cast<const bfrag8*>(ywAs + ab0 +
                                                          headStride + cc * 512);
#pragma unroll
            for (int st = 0; st < 8; ++st) {
                bfrag8 bf = *reinterpret_cast<const bfrag8*>(
                    tSw + (st * 6 + cc) * 512);
                accv[0][st] = __builtin_amdgcn_mfma_f32_16x16x32_bf16(
                    af0, bf, accv[0][st], 0, 0, 0);
                accv[1][st] = __builtin_amdgcn_mfma_f32_16x16x32_bf16(
                    af1, bf, accv[1][st], 0, 0, 0);
            }
        }

        // scale+mask+exp (no max-sub; masked scores exp(0)=1 participate,
        // exactly as the reference's softmax over zeroed scores)
#pragma unroll
        for (int p = 0; p < 2; ++p) {
            const int k = 2 * kp + p;
            const float sk = sc_s[k];
            float lrow[4];
#pragma unroll
            for (int r = 0; r < 4; ++r) {
                const float ybk = yb_s[k][lg * 4 + r];
                const float cf = sk * ymr[r] * invs;
                float ls = 0.f;
#pragma unroll
                for (int st = 0; st < 8; ++st) {
                    float v = (accv[p][st][r] + ybk) * cf * tm2r[st];
                    float e = __expf(v);
                    accv[p][st][r] = e;
                    ls += e;
                }
                lrow[r] = ls;
            }
#pragma unroll
            for (int d = 1; d < 16; d <<= 1)
#pragma unroll
                for (int r = 0; r < 4; ++r) lrow[r] += __shfl_xor(lrow[r], d);
            if (l15 == 0) {
#pragma unroll
                for (int r = 0; r < 4; ++r)
                    lred[kp & 1][p][lg * 4 + r][w] = lrow[r];
            }
        }
        __syncthreads();
#pragma unroll
        for (int p = 0; p < 2; ++p)
#pragma unroll
            for (int r = 0; r < 4; ++r) {
                const float4 v0 = *reinterpret_cast<const float4*>(
                    &lred[kp & 1][p][lg * 4 + r][0]);
                const float4 v1 = *reinterpret_cast<const float4*>(
                    &lred[kp & 1][p][lg * 4 + r][4]);
                const float rl =
                    1.0f /
                    (v0.x + v0.y + v0.z + v0.w + v1.x + v1.y + v1.z + v1.w);
#pragma unroll
                for (int st = 0; st < 8; ++st)
                    accsum[st][r] += accv[p][st][r] * rl;
            }
    }

    // dump prob-sums to LDS (wave-private region; read back by same wave)
#pragma unroll
    for (int st = 0; st < 8; ++st)
        *reinterpret_cast<f32x4*>(&lds_acc[w][st][l][0]) = accsum[st];
    __builtin_amdgcn_s_waitcnt(0);  // lgkmcnt(0): own-wave ds_writes visible

    // ---------------- context phase ----------------
    // wave w contracts s in [w*128,(w+1)*128) against textC; A-frags gathered
    // from its own lds_acc region (transpose) and packed to bf16.
    const short* tC = reinterpret_cast<const short*>(textC);
    f32x4 cacc[12];
#pragma unroll
    for (int c = 0; c < 12; ++c) cacc[c] = (f32x4){0.f, 0.f, 0.f, 0.f};

#pragma unroll
    for (int sc = 0; sc < 4; ++sc) {
        const int scg = w * 4 + sc;
        union {
            bfrag8 v8;
            unsigned u[4];
        } A;
#pragma unroll
        for (int jp = 0; jp < 4; ++jp) {
            const int s0 = scg * 32 + lg * 8 + jp * 2;
            const int reg0 = s0 >> 7, st0 = (s0 >> 4) & 7;
            const int lo0 = (s0 & 15) | ((l15 >> 2) << 4);
            const int s1 = s0 + 1;
            const int lo1 = (s1 & 15) | ((l15 >> 2) << 4);
            const int ro = l15 & 3;
            float a = lds_acc[reg0][st0][lo0][ro];
            float bb2 = lds_acc[s1 >> 7][(s1 >> 4) & 7][lo1][ro];
            A.u[jp] = pk2(a, bb2);
        }
#pragma unroll
        for (int ctt = 0; ctt < 12; ++ctt) {
            bfrag8 bf = *reinterpret_cast<const bfrag8*>(
                tC + (((size_t)b * 12 + ctt) * 32 + scg) * 512 + (size_t)l * 8);
            cacc[ctt] =
                __builtin_amdgcn_mfma_f32_16x16x32_bf16(A.v8, bf, cacc[ctt], 0, 0, 0);
        }
    }
    __syncthreads();  // all lds_acc reads done before overwrite as 'part'

    float(*part)[16][192] = reinterpret_cast<float(*)[16][192]>(
        &lds_acc[0][0][0][0]);  // 4*16*192*4B = 49 KB, fits in lds_acc
    if (w < 4) {
#pragma unroll
        for (int ctt = 0; ctt < 12; ++ctt)
#pragma unroll
            for (int r = 0; r < 4; ++r)
                part[w][lg * 4 + r][ctt * 16 + l15] = cacc[ctt][r];
    }
    __syncthreads();
    if (w >= 4) {
#pragma unroll
        for (int ctt = 0; ctt < 12; ++ctt)
#pragma unroll
            for (int r = 0; r < 4; ++r)
                part[w - 4][lg * 4 + r][ctt * 16 + l15] += cacc[ctt][r];
    }
    __syncthreads();

    // epilogue: out[b,c,t0..t0+15] = y + ctx[t][c%192] + ge[b,c]
    const float* yb_ = y + (size_t)b * CC * TT;
    float* ob = out + (size_t)b * CC * TT;
    const float* geb = ge + b * CC;
    for (int c = tid; c < CC; c += 512) {
        const float gev = geb[c];
        const int cm = c % CT;
        const float4* ysrc =
            reinterpret_cast<const float4*>(yb_ + (size_t)c * TT + t0);
        float4* od = reinterpret_cast<float4*>(ob + (size_t)c * TT + t0);
#pragma unroll
        for (int i4 = 0; i4 < 4; ++i4) {
            float4 v = ysrc[i4];
            const int row = i4 * 4;
            v.x += part[0][row + 0][cm] + part[1][row + 0][cm] +
                   part[2][row + 0][cm] + part[3][row + 0][cm] + gev;
            v.y += part[0][row + 1][cm] + part[1][row + 1][cm] +
                   part[2][row + 1][cm] + part[3][row + 1][cm] + gev;
            v.z += part[0][row + 2][cm] + part[1][row + 2][cm] +
                   part[2][row + 2][cm] + part[3][row + 2][cm] + gev;
            v.w += part[0][row + 3][cm] + part[1][row + 3][cm] +
                   part[2][row + 3][cm] + part[3][row + 3][cm] + gev;
            od[i4] = v;
        }
    }
}

// ---------------------------------------------------------------------------
extern "C" void kernel_launch(void* const* d_in, const int* in_sizes, int n_in,
                              void* d_out, int out_size, void* d_ws,
                              size_t ws_size, hipStream_t stream) {
    const float* y      = (const float*)d_in[0];
    const float* ymask  = (const float*)d_in[1];
    const float* text   = (const float*)d_in[2];
    const float* tmask  = (const float*)d_in[3];
    const float* ge     = (const float*)d_in[4];
    const float* W      = (const float*)d_in[5];
    const float* bias   = (const float*)d_in[6];
    const float* scale  = (const float*)d_in[7];
    float* out = (float*)d_out;

    // workspace carve-up (bytes)
    char* ws = (char*)d_ws;
    __hip_bfloat16* ywA   = (__hip_bfloat16*)ws;                 // 37,748,736
    float*          ybws  = (float*)(ws + 37748736);             //    393,216
    __hip_bfloat16* textS = (__hip_bfloat16*)(ws + 38141952);    //  1,572,864
    __hip_bfloat16* textC = (__hip_bfloat16*)(ws + 39714816);    //  1,572,864
    __hip_bfloat16* yP    = (__hip_bfloat16*)(ws + 58064896);    // 12,582,912
    __hip_bfloat16* WP    = (__hip_bfloat16*)(ws + 70647808);    //  3,538,944

    k_pack_text<<<dim3(BB, 8), 256, 0, stream>>>(text, textS, textC);
    k_pack_y<<<dim3(BB, 16), 256, 0, stream>>>(y, yP);
    k_pack_w<<<dim3(KK, 8), 256, 0, stream>>>(W, WP);
    k_yw_mfma<<<1536, 256, 0, stream>>>(yP, WP, ywA);
    k_yb2<<<dim3(TT / 64, BB), 256, 0, stream>>>(y, bias, ybws);
    k_attn_fused<<<512, 512, 0, stream>>>(ymask, tmask, scale, ywA, ybws,
                                          textS, textC, y, ge, out);
}

// Round 9
// 322.094 us; speedup vs baseline: 1.2967x; 1.2967x over previous
//
#include <hip/hip_runtime.h>
#include <hip/hip_bf16.h>

// Problem constants
#define BB 4
#define CC 768
#define CT 192
#define TT 2048
#define SS 1024
#define KK 12

typedef __attribute__((ext_vector_type(8))) short bfrag8;  // 8 bf16 = 4 VGPR
typedef __attribute__((ext_vector_type(4))) float f32x4;

// ---------------------------------------------------------------------------
// Fragment-layout convention (16x16x32 bf16 MFMA):
//   A: row m = lane&15, k-slot = 32*cc + (lane>>4)*8 + j
//   B: col n = lane&15, k-slot = 32*cc + (lane>>4)*8 + j
//   D: col n = lane&15, row m = (lane>>4)*4 + reg   (HW-verified)
// A/B use the SAME slot->k map so the contraction is exact.
//
// HARD CONSTRAINT (measured R7/R8): this toolchain pins the VGPR budget at
// 128 for these kernels regardless of waves_per_eu / LDS size. All designs
// below are sized to ~110 live VGPRs.
// ---------------------------------------------------------------------------

__device__ inline unsigned pk2(float a, float b) {
    __hip_bfloat162 h2;
    h2.x = __float2bfloat16(a);
    h2.y = __float2bfloat16(b);
    return *reinterpret_cast<unsigned*>(&h2);
}
__device__ inline float unpk_lo(unsigned u) {
    return __uint_as_float(u << 16);
}
__device__ inline float unpk_hi(unsigned u) {
    return __uint_as_float(u & 0xffff0000u);
}

// Pack text (fp32 [b][ct][s]) into B-fragment layouts (bf16):
//  textS [b][st:64][cc:6][l:64][j:8]   (score GEMM: K=ct, N=s)
//  textC [b][ctt:12][scg:32][l:64][j:8] (context GEMM: K=s, N=ct)
__global__ void k_pack_text(const float* __restrict__ text,
                            __hip_bfloat16* __restrict__ textS,
                            __hip_bfloat16* __restrict__ textC) {
    const int b = blockIdx.x;
    const float* tb = text + (size_t)b * CT * SS;
    const int stride = blockDim.x * gridDim.y;
    const int base = threadIdx.x + blockIdx.y * blockDim.x;
    for (int e = base; e < 64 * 6 * 512; e += stride) {
        int jj = e & 7, l = (e >> 3) & 63, cc = (e >> 9) % 6, st = e / 3072;
        int ct = cc * 32 + ((l >> 4) << 3) + jj;
        int s = st * 16 + (l & 15);
        textS[(size_t)b * 196608 + e] = __float2bfloat16(tb[(size_t)ct * SS + s]);
    }
    for (int e = base; e < 12 * 32 * 512; e += stride) {
        int jj = e & 7, l = (e >> 3) & 63, scg = (e >> 9) & 31, ctt = e / 16384;
        int ct = ctt * 16 + (l & 15);
        int s = scg * 32 + ((l >> 4) << 3) + jj;
        textC[(size_t)b * 196608 + e] = __float2bfloat16(tb[(size_t)ct * SS + s]);
    }
}

// Pack y (fp32 [b][o][t]) into A-frag layout yP[b][tt:128][oc:24][l:64][j:8]
__global__ void k_pack_y(const float* __restrict__ y,
                         __hip_bfloat16* __restrict__ yP) {
    const int b = blockIdx.x;
    const float* yb_ = y + (size_t)b * CC * TT;
    const int stride = blockDim.x * gridDim.y;
    for (int e = threadIdx.x + blockIdx.y * blockDim.x; e < 128 * 24 * 512;
         e += stride) {
        int j = e & 7, l = (e >> 3) & 63, oc = (e >> 9) % 24, tt = e / 12288;
        int t = tt * 16 + (l & 15);
        int o = oc * 32 + ((l >> 4) << 3) + j;
        yP[(size_t)b * 1572864 + e] = __float2bfloat16(yb_[(size_t)o * TT + t]);
    }
}

// Pack W (fp32 [k][o][ct]) into B-frag layout WP[k][nt:12][oc:24][l:64][j:8]
__global__ void k_pack_w(const float* __restrict__ W,
                         __hip_bfloat16* __restrict__ WP) {
    const int k = blockIdx.x;
    const float* wk = W + (size_t)k * CC * CT;
    const int stride = blockDim.x * gridDim.y;
    for (int e = threadIdx.x + blockIdx.y * blockDim.x; e < 12 * 24 * 512;
         e += stride) {
        int j = e & 7, l = (e >> 3) & 63, oc = (e >> 9) % 24, nt = e / 12288;
        int ct = nt * 16 + (l & 15);
        int o = oc * 32 + ((l >> 4) << 3) + j;
        WP[(size_t)k * 147456 + e] = __float2bfloat16(wk[(size_t)o * CT + ct]);
    }
}

// ---------------------------------------------------------------------------
// yW via MFMA. 1536 blocks, XCD-swizzled: XCD x handles b = x&3 only.
// R9: wave = 3 nt x 4 ttg (was 12 nt x 1 ttg) -> each bf B-frag load feeds
// 4 MFMAs (was 1): block global traffic 1.28 MB -> 672 KB.
// acc[3][4] = 48 VGPR + af[4] 16 + bf 4: fits 128.
// ---------------------------------------------------------------------------
__global__ __launch_bounds__(256, 2) void k_yw_mfma(
    const __hip_bfloat16* __restrict__ yP, const __hip_bfloat16* __restrict__ WP,
    __hip_bfloat16* __restrict__ ywA) {
    const int i = blockIdx.x;
    const int x = i & 7, j = i >> 3;
    const int b = x & 3;
    const int k = j >> 4;
    const int tx = (j & 15) | ((x >> 2) << 4);
    const int kb = k * BB + b;

    const int tid = threadIdx.x;
    const int w = tid >> 6, l = tid & 63;
    const int l15 = l & 15, lg = l >> 4;
    const int ttg0 = tx * 4;
    const int nt0 = 3 * w;

    const short* ypb = reinterpret_cast<const short*>(yP) +
                       (((size_t)b * 128 + ttg0) * 24) * 512 + (size_t)l * 8;
    const short* wp = reinterpret_cast<const short*>(WP) +
                      (size_t)k * 147456 + (size_t)l * 8;

    f32x4 acc[3][4];
#pragma unroll
    for (int n = 0; n < 3; ++n)
#pragma unroll
        for (int tg = 0; tg < 4; ++tg) acc[n][tg] = (f32x4){0.f, 0.f, 0.f, 0.f};

    for (int oc = 0; oc < 24; ++oc) {
        bfrag8 af[4];
#pragma unroll
        for (int tg = 0; tg < 4; ++tg)
            af[tg] = *reinterpret_cast<const bfrag8*>(ypb + (tg * 24 + oc) * 512);
#pragma unroll
        for (int n = 0; n < 3; ++n) {
            bfrag8 bf = *reinterpret_cast<const bfrag8*>(
                wp + ((nt0 + n) * 24 + oc) * 512);
#pragma unroll
            for (int tg = 0; tg < 4; ++tg)
                acc[n][tg] = __builtin_amdgcn_mfma_f32_16x16x32_bf16(
                    af[tg], bf, acc[n][tg], 0, 0, 0);
        }
    }

#pragma unroll
    for (int n = 0; n < 3; ++n) {
        const int nt = nt0 + n;
#pragma unroll
        for (int tg = 0; tg < 4; ++tg) {
            const size_t obase = ((size_t)kb * 128 + ttg0 + tg) * 3072;
#pragma unroll
            for (int r = 0; r < 4; ++r) {
                const int ct = nt * 16 + l15;
                const int lane2 = (lg * 4 + r) | (((ct >> 3) & 3) << 4);
                ywA[obase + (size_t)(ct >> 5) * 512 + lane2 * 8 + (ct & 7)] =
                    __float2bfloat16(acc[n][tg][r]);
            }
        }
    }
}

// ---------------------------------------------------------------------------
// yb[k,b,t] for all 12 k in one pass over y.
// ---------------------------------------------------------------------------
__global__ __launch_bounds__(256) void k_yb2(const float* __restrict__ y,
                                             const float* __restrict__ bias,
                                             float* __restrict__ yb) {
    const int b = blockIdx.y;
    const int t0 = blockIdx.x * 64;
    const int tid = threadIdx.x;
    const int tl = tid & 63, g = tid >> 6;

    __shared__ float bs[KK][CC];
    __shared__ float pb[4][64][KK];
    for (int i = tid; i < KK * CC; i += 256) bs[i / CC][i % CC] = bias[i];
    __syncthreads();

    float p[KK];
#pragma unroll
    for (int k = 0; k < KK; ++k) p[k] = 0.f;
    const float* yb_ = y + (size_t)b * CC * TT + t0 + tl;
    for (int o = g * 192; o < g * 192 + 192; ++o) {
        float v = yb_[(size_t)o * TT];
#pragma unroll
        for (int k = 0; k < KK; ++k) p[k] += v * bs[k][o];
    }
#pragma unroll
    for (int k = 0; k < KK; ++k) pb[g][tl][k] = p[k];
    __syncthreads();
    for (int i = tid; i < 64 * KK; i += 256) {
        int tt = i / KK, k = i % KK;
        float s = pb[0][tt][k] + pb[1][tt][k] + pb[2][tt][k] + pb[3][tt][k];
        yb[((size_t)k * BB + b) * TT + t0 + tt] = s;
    }
}

// ---------------------------------------------------------------------------
// FUSED attn, R9: head-paired scores with exp values streamed to LDS as
// packed bf16 (exp_buf) instead of held in VGPRs -> live set ~106 VGPR,
// no spill at the 128 cap. st-outer/cc-inner; af[2][6] preloaded per pair.
// No max-sub (mathematically identical; scores O(+-10), exp fits bf16).
// lds_acc[w][st][l][r] accumulates sum_k prob (fp32 RMW, wave-private).
// After head loop: context MFMA from lds_acc transpose + epilogue.
// 512 threads = 8 waves; wave w owns s in [w*128,(w+1)*128).
// lred double-buffered by kp-parity -> single barrier per head-pair.
// ---------------------------------------------------------------------------
__global__ __launch_bounds__(512) void k_attn_fused(
    const float* __restrict__ ymask, const float* __restrict__ tmask,
    const float* __restrict__ scale, const __hip_bfloat16* __restrict__ ywA,
    const float* __restrict__ ybws, const __hip_bfloat16* __restrict__ textS,
    const __hip_bfloat16* __restrict__ textC, const float* __restrict__ y,
    const float* __restrict__ ge, float* __restrict__ out) {
    const int i = blockIdx.x;
    const int x = i & 7;
    const int b = x & 3;
    const int tt = (i >> 3) + ((x >> 2) << 6);
    const int t0 = tt * 16;
    const int tid = threadIdx.x;
    const int w = tid >> 6;       // 0..7
    const int l = tid & 63;
    const int l15 = l & 15, lg = l >> 4;
    const int ws0 = w * 128;

    __shared__ float lds_acc[8][8][64][4];   // 64 KB: prob-sum accumulator
    __shared__ uint2 exp_buf[2][8][8][64];   // 64 KB: [p][w][st][l] bf16 exp x4
    __shared__ float yb_s[KK][16];
    __shared__ float sc_s[KK];
    __shared__ __align__(16) float lred[2][2][16][8];  // [kp&1][p][row][w]

    if (tid < 192)
        yb_s[tid >> 4][tid & 15] =
            ybws[(size_t)((tid >> 4) * BB + b) * TT + t0 + (tid & 15)];
    if (tid < KK) sc_s[tid] = scale[tid];
    const f32x4 zero4 = (f32x4){0.f, 0.f, 0.f, 0.f};
#pragma unroll
    for (int st = 0; st < 8; ++st)
        *reinterpret_cast<f32x4*>(&lds_acc[w][st][l][0]) = zero4;
    __syncthreads();

    float tm2r[8];
#pragma unroll
    for (int st = 0; st < 8; ++st) {
        float m = tmask[b * SS + ws0 + st * 16 + l15];
        tm2r[st] = m * m;
    }
    float ymr[4];
#pragma unroll
    for (int r = 0; r < 4; ++r) ymr[r] = ymask[b * TT + t0 + lg * 4 + r];
    const float invs = 0.03608439182435161f;  // 1/sqrt(768)

    const short* ywAs = reinterpret_cast<const short*>(ywA);
    const short* tS = reinterpret_cast<const short*>(textS);
    const short* tSw = tS + (((size_t)b * 64 + w * 8) * 6) * 512 + (size_t)l * 8;
    const size_t headStride = (size_t)BB * 128 * 3072;  // shorts per head

    for (int kp = 0; kp < 6; ++kp) {
        // preload both heads' A-frags: 12 x 16B = 48 VGPR
        bfrag8 af[2][6];
        const size_t ab0 =
            (((size_t)(2 * kp * BB + b) * 128 + tt) * 6) * 512 + (size_t)l * 8;
#pragma unroll
        for (int cc = 0; cc < 6; ++cc) {
            af[0][cc] = *reinterpret_cast<const bfrag8*>(ywAs + ab0 + cc * 512);
            af[1][cc] = *reinterpret_cast<const bfrag8*>(ywAs + ab0 +
                                                         headStride + cc * 512);
        }
        // per-head scale factors
        float cfr[2][4], ybk[2][4];
#pragma unroll
        for (int p = 0; p < 2; ++p) {
            const int k = 2 * kp + p;
            const float sk = sc_s[k];
#pragma unroll
            for (int r = 0; r < 4; ++r) {
                ybk[p][r] = yb_s[k][lg * 4 + r];
                cfr[p][r] = sk * ymr[r] * invs;
            }
        }

        float lrow[2][4] = {{0.f, 0.f, 0.f, 0.f}, {0.f, 0.f, 0.f, 0.f}};
#pragma unroll
        for (int st = 0; st < 8; ++st) {
            f32x4 av0 = zero4, av1 = zero4;
#pragma unroll
            for (int cc = 0; cc < 6; ++cc) {
                bfrag8 bf = *reinterpret_cast<const bfrag8*>(
                    tSw + (st * 6 + cc) * 512);
                av0 = __builtin_amdgcn_mfma_f32_16x16x32_bf16(af[0][cc], bf,
                                                              av0, 0, 0, 0);
                av1 = __builtin_amdgcn_mfma_f32_16x16x32_bf16(af[1][cc], bf,
                                                              av1, 0, 0, 0);
            }
            // scale+mask+exp (masked scores exp(0)=1 participate, as ref)
#pragma unroll
            for (int r = 0; r < 4; ++r) {
                float e0 = __expf((av0[r] + ybk[0][r]) * cfr[0][r] * tm2r[st]);
                float e1 = __expf((av1[r] + ybk[1][r]) * cfr[1][r] * tm2r[st]);
                av0[r] = e0;
                av1[r] = e1;
                lrow[0][r] += e0;
                lrow[1][r] += e1;
            }
            exp_buf[0][w][st][l] =
                make_uint2(pk2(av0[0], av0[1]), pk2(av0[2], av0[3]));
            exp_buf[1][w][st][l] =
                make_uint2(pk2(av1[0], av1[1]), pk2(av1[2], av1[3]));
        }

        // block-wide denominator over S=1024
#pragma unroll
        for (int d = 1; d < 16; d <<= 1)
#pragma unroll
            for (int p = 0; p < 2; ++p)
#pragma unroll
                for (int r = 0; r < 4; ++r)
                    lrow[p][r] += __shfl_xor(lrow[p][r], d);
        if (l15 == 0) {
#pragma unroll
            for (int p = 0; p < 2; ++p)
#pragma unroll
                for (int r = 0; r < 4; ++r)
                    lred[kp & 1][p][lg * 4 + r][w] = lrow[p][r];
        }
        __syncthreads();
        float rl[2][4];
#pragma unroll
        for (int p = 0; p < 2; ++p)
#pragma unroll
            for (int r = 0; r < 4; ++r) {
                const float4 v0 = *reinterpret_cast<const float4*>(
                    &lred[kp & 1][p][lg * 4 + r][0]);
                const float4 v1 = *reinterpret_cast<const float4*>(
                    &lred[kp & 1][p][lg * 4 + r][4]);
                rl[p][r] = 1.0f / (v0.x + v0.y + v0.z + v0.w + v1.x + v1.y +
                                   v1.z + v1.w);
            }
        // read exp back, normalize, accumulate (all LDS, wave-private)
#pragma unroll
        for (int st = 0; st < 8; ++st) {
            const uint2 e0 = exp_buf[0][w][st][l];
            const uint2 e1 = exp_buf[1][w][st][l];
            f32x4 cur = *reinterpret_cast<f32x4*>(&lds_acc[w][st][l][0]);
            cur[0] += unpk_lo(e0.x) * rl[0][0] + unpk_lo(e1.x) * rl[1][0];
            cur[1] += unpk_hi(e0.x) * rl[0][1] + unpk_hi(e1.x) * rl[1][1];
            cur[2] += unpk_lo(e0.y) * rl[0][2] + unpk_lo(e1.y) * rl[1][2];
            cur[3] += unpk_hi(e0.y) * rl[0][3] + unpk_hi(e1.y) * rl[1][3];
            *reinterpret_cast<f32x4*>(&lds_acc[w][st][l][0]) = cur;
        }
        // lred[kp&1] safe to reuse at kp+2: reads above precede barrier(kp+1)
    }
    __builtin_amdgcn_s_waitcnt(0);  // own-wave lds_acc writes visible

    // ---------------- context phase ----------------
    // wave w contracts s in [w*128,(w+1)*128) against textC; A-frags gathered
    // from its own lds_acc region (transpose) and packed to bf16.
    const short* tC = reinterpret_cast<const short*>(textC);
    f32x4 cacc[12];
#pragma unroll
    for (int c = 0; c < 12; ++c) cacc[c] = (f32x4){0.f, 0.f, 0.f, 0.f};

#pragma unroll
    for (int sc = 0; sc < 4; ++sc) {
        const int scg = w * 4 + sc;
        union {
            bfrag8 v8;
            unsigned u[4];
        } A;
#pragma unroll
        for (int jp = 0; jp < 4; ++jp) {
            const int s0 = scg * 32 + lg * 8 + jp * 2;
            const int reg0 = s0 >> 7, st0 = (s0 >> 4) & 7;
            const int lo0 = (s0 & 15) | ((l15 >> 2) << 4);
            const int s1 = s0 + 1;
            const int lo1 = (s1 & 15) | ((l15 >> 2) << 4);
            const int ro = l15 & 3;
            float a = lds_acc[reg0][st0][lo0][ro];
            float bb2 = lds_acc[s1 >> 7][(s1 >> 4) & 7][lo1][ro];
            A.u[jp] = pk2(a, bb2);
        }
#pragma unroll
        for (int ctt = 0; ctt < 12; ++ctt) {
            bfrag8 bf = *reinterpret_cast<const bfrag8*>(
                tC + (((size_t)b * 12 + ctt) * 32 + scg) * 512 + (size_t)l * 8);
            cacc[ctt] = __builtin_amdgcn_mfma_f32_16x16x32_bf16(A.v8, bf,
                                                                cacc[ctt], 0, 0, 0);
        }
    }
    __syncthreads();  // all lds_acc reads done before overwrite as 'part'

    float(*part)[16][192] = reinterpret_cast<float(*)[16][192]>(
        &lds_acc[0][0][0][0]);  // 4*16*192*4B = 49 KB, fits in lds_acc
    if (w < 4) {
#pragma unroll
        for (int ctt = 0; ctt < 12; ++ctt)
#pragma unroll
            for (int r = 0; r < 4; ++r)
                part[w][lg * 4 + r][ctt * 16 + l15] = cacc[ctt][r];
    }
    __syncthreads();
    if (w >= 4) {
#pragma unroll
        for (int ctt = 0; ctt < 12; ++ctt)
#pragma unroll
            for (int r = 0; r < 4; ++r)
                part[w - 4][lg * 4 + r][ctt * 16 + l15] += cacc[ctt][r];
    }
    __syncthreads();

    // epilogue: out[b,c,t0..t0+15] = y + ctx[t][c%192] + ge[b,c]
    const float* yb_ = y + (size_t)b * CC * TT;
    float* ob = out + (size_t)b * CC * TT;
    const float* geb = ge + b * CC;
    for (int c = tid; c < CC; c += 512) {
        const float gev = geb[c];
        const int cm = c % CT;
        const float4* ysrc =
            reinterpret_cast<const float4*>(yb_ + (size_t)c * TT + t0);
        float4* od = reinterpret_cast<float4*>(ob + (size_t)c * TT + t0);
#pragma unroll
        for (int i4 = 0; i4 < 4; ++i4) {
            float4 v = ysrc[i4];
            const int row = i4 * 4;
            v.x += part[0][row + 0][cm] + part[1][row + 0][cm] +
                   part[2][row + 0][cm] + part[3][row + 0][cm] + gev;
            v.y += part[0][row + 1][cm] + part[1][row + 1][cm] +
                   part[2][row + 1][cm] + part[3][row + 1][cm] + gev;
            v.z += part[0][row + 2][cm] + part[1][row + 2][cm] +
                   part[2][row + 2][cm] + part[3][row + 2][cm] + gev;
            v.w += part[0][row + 3][cm] + part[1][row + 3][cm] +
                   part[2][row + 3][cm] + part[3][row + 3][cm] + gev;
            od[i4] = v;
        }
    }
}

// ---------------------------------------------------------------------------
extern "C" void kernel_launch(void* const* d_in, const int* in_sizes, int n_in,
                              void* d_out, int out_size, void* d_ws,
                              size_t ws_size, hipStream_t stream) {
    const float* y      = (const float*)d_in[0];
    const float* ymask  = (const float*)d_in[1];
    const float* text   = (const float*)d_in[2];
    const float* tmask  = (const float*)d_in[3];
    const float* ge     = (const float*)d_in[4];
    const float* W      = (const float*)d_in[5];
    const float* bias   = (const float*)d_in[6];
    const float* scale  = (const float*)d_in[7];
    float* out = (float*)d_out;

    // workspace carve-up (bytes)
    char* ws = (char*)d_ws;
    __hip_bfloat16* ywA   = (__hip_bfloat16*)ws;                 // 37,748,736
    float*          ybws  = (float*)(ws + 37748736);             //    393,216
    __hip_bfloat16* textS = (__hip_bfloat16*)(ws + 38141952);    //  1,572,864
    __hip_bfloat16* textC = (__hip_bfloat16*)(ws + 39714816);    //  1,572,864
    __hip_bfloat16* yP    = (__hip_bfloat16*)(ws + 58064896);    // 12,582,912
    __hip_bfloat16* WP    = (__hip_bfloat16*)(ws + 70647808);    //  3,538,944

    k_pack_text<<<dim3(BB, 8), 256, 0, stream>>>(text, textS, textC);
    k_pack_y<<<dim3(BB, 16), 256, 0, stream>>>(y, yP);
    k_pack_w<<<dim3(KK, 8), 256, 0, stream>>>(W, WP);
    k_yw_mfma<<<1536, 256, 0, stream>>>(yP, WP, ywA);
    k_yb2<<<dim3(TT / 64, BB), 256, 0, stream>>>(y, bias, ybws);
    k_attn_fused<<<512, 512, 0, stream>>>(ymask, tmask, scale, ywA, ybws,
                                          textS, textC, y, ge, out);
}

// Round 10
// 227.948 us; speedup vs baseline: 1.8323x; 1.4130x over previous
//
#include <hip/hip_runtime.h>
#include <hip/hip_bf16.h>

// Problem constants
#define BB 4
#define CC 768
#define CT 192
#define TT 2048
#define SS 1024
#define KK 12

typedef __attribute__((ext_vector_type(8))) short bfrag8;  // 8 bf16 = 4 VGPR
typedef __attribute__((ext_vector_type(4))) float f32x4;

// ---------------------------------------------------------------------------
// Fragment-layout convention (16x16x32 bf16 MFMA):
//   A: row m = lane&15, k-slot = 32*cc + (lane>>4)*8 + j
//   B: col n = lane&15, k-slot = 32*cc + (lane>>4)*8 + j
//   D: col n = lane&15, row m = (lane>>4)*4 + reg   (HW-verified)
// A/B use the SAME slot->k map so the contraction is exact.
//
// HARD CONSTRAINT (measured R7/R8): the toolchain pins VGPR budget at 128
// for these kernels regardless of waves_per_eu / LDS size. Designs sized
// to ~110 live VGPRs.
// ---------------------------------------------------------------------------

__device__ inline unsigned pk2(float a, float b) {
    __hip_bfloat162 h2;
    h2.x = __float2bfloat16(a);
    h2.y = __float2bfloat16(b);
    return *reinterpret_cast<unsigned*>(&h2);
}
__device__ inline float unpk_lo(unsigned u) { return __uint_as_float(u << 16); }
__device__ inline float unpk_hi(unsigned u) {
    return __uint_as_float(u & 0xffff0000u);
}

// ---------------------------------------------------------------------------
// ONE pack kernel, 256 blocks:
//   blk 0..31   : textS/textC  (b = blk>>3, part = blk&7)
//   blk 32..127 : WP           (k = (blk-32)>>3, part = (blk-32)&7)
//   blk 128..255: yP via LDS transpose (b = idx>>5, tq = idx&31; 64 t each)
// Branch is uniform per block (blockIdx-based) -> barriers legal.
// ---------------------------------------------------------------------------
__global__ __launch_bounds__(256) void k_pack_all(
    const float* __restrict__ text, const float* __restrict__ W,
    const float* __restrict__ y, __hip_bfloat16* __restrict__ textS,
    __hip_bfloat16* __restrict__ textC, __hip_bfloat16* __restrict__ WP,
    __hip_bfloat16* __restrict__ yP) {
    __shared__ float tile[32][64];  // 8 KB (y branch only)
    const int blk = blockIdx.x;
    const int tid = threadIdx.x;

    if (blk < 32) {
        const int b = blk >> 3;
        const float* tb = text + (size_t)b * CT * SS;
        const int base = tid + (blk & 7) * 256;
        for (int e = base; e < 64 * 6 * 512; e += 2048) {
            int jj = e & 7, l = (e >> 3) & 63, cc = (e >> 9) % 6, st = e / 3072;
            int ct = cc * 32 + ((l >> 4) << 3) + jj;
            int s = st * 16 + (l & 15);
            textS[(size_t)b * 196608 + e] =
                __float2bfloat16(tb[(size_t)ct * SS + s]);
        }
        for (int e = base; e < 12 * 32 * 512; e += 2048) {
            int jj = e & 7, l = (e >> 3) & 63, scg = (e >> 9) & 31,
                ctt = e / 16384;
            int ct = ctt * 16 + (l & 15);
            int s = scg * 32 + ((l >> 4) << 3) + jj;
            textC[(size_t)b * 196608 + e] =
                __float2bfloat16(tb[(size_t)ct * SS + s]);
        }
    } else if (blk < 128) {
        const int k = (blk - 32) >> 3;
        const float* wk = W + (size_t)k * CC * CT;
        const int base = tid + ((blk - 32) & 7) * 256;
        for (int e = base; e < 12 * 24 * 512; e += 2048) {
            int j = e & 7, l = (e >> 3) & 63, oc = (e >> 9) % 24, nt = e / 12288;
            int ct = nt * 16 + (l & 15);
            int o = oc * 32 + ((l >> 4) << 3) + j;
            WP[(size_t)k * 147456 + e] =
                __float2bfloat16(wk[(size_t)o * CT + ct]);
        }
    } else {
        // y pack: block = (b, tq); covers all 768 o x 64 t, 24 chunks of 32 o.
        const int idx = blk - 128;
        const int b = idx >> 5;
        const int tq = idx & 31;
        const int t0 = tq * 64;
        const float* yb_ = y + (size_t)b * CC * TT;
        const int w = tid >> 6, l = tid & 63;
        const int l15 = l & 15, lg = l >> 4;
        const int row0 = tid >> 4;   // 0..15
        const int c4 = tid & 15;     // float4 column

        for (int oc = 0; oc < 24; ++oc) {
            // stage 32 o x 64 t, coalesced row reads (full 64-B lines)
#pragma unroll
            for (int h = 0; h < 2; ++h) {
                const int row = row0 + h * 16;
                const float4 v = *reinterpret_cast<const float4*>(
                    yb_ + (size_t)(oc * 32 + row) * TT + t0 + c4 * 4);
                *reinterpret_cast<float4*>(&tile[row][c4 * 4]) = v;
            }
            __syncthreads();
            // wave w emits the A-frag for tt = tq*4 + w
            union {
                bfrag8 v8;
                short u[8];
            } A;
#pragma unroll
            for (int j = 0; j < 8; ++j)
                A.u[j] = (short)__bfloat16_as_ushort(
                    __float2bfloat16(tile[lg * 8 + j][w * 16 + l15]));
            __hip_bfloat16* dst =
                yP + (((size_t)(b * 128 + tq * 4 + w) * 24 + oc) * 512) +
                (size_t)l * 8;
            *reinterpret_cast<bfrag8*>(dst) = A.v8;
            __syncthreads();
        }
    }
}

// ---------------------------------------------------------------------------
// yW via MFMA. 1536 blocks, XCD-swizzled: XCD x handles b = x&3 only.
// Wave = 3 nt x 4 ttg. Epilogue via LDS bounce: acc -> ot[4][16][197] f32
// (pad 197 -> ~2-way banks) -> wave w re-reads tile tg=w in A-frag order ->
// 6 coalesced b128 stores/thread (replaces 48 scalar 2-B stores: ~19M store
// instrs -> 2.4M, was ~30 us of store issue).
// ---------------------------------------------------------------------------
__global__ __launch_bounds__(256, 2) void k_yw_mfma(
    const __hip_bfloat16* __restrict__ yP, const __hip_bfloat16* __restrict__ WP,
    __hip_bfloat16* __restrict__ ywA) {
    const int i = blockIdx.x;
    const int x = i & 7, j = i >> 3;
    const int b = x & 3;
    const int k = j >> 4;
    const int tx = (j & 15) | ((x >> 2) << 4);
    const int kb = k * BB + b;

    const int tid = threadIdx.x;
    const int w = tid >> 6, l = tid & 63;
    const int l15 = l & 15, lg = l >> 4;
    const int ttg0 = tx * 4;
    const int nt0 = 3 * w;

    __shared__ float ot[4][16][197];  // 50.4 KB

    const short* ypb = reinterpret_cast<const short*>(yP) +
                       (((size_t)b * 128 + ttg0) * 24) * 512 + (size_t)l * 8;
    const short* wp = reinterpret_cast<const short*>(WP) +
                      (size_t)k * 147456 + (size_t)l * 8;

    f32x4 acc[3][4];
#pragma unroll
    for (int n = 0; n < 3; ++n)
#pragma unroll
        for (int tg = 0; tg < 4; ++tg) acc[n][tg] = (f32x4){0.f, 0.f, 0.f, 0.f};

    for (int oc = 0; oc < 24; ++oc) {
        bfrag8 af[4];
#pragma unroll
        for (int tg = 0; tg < 4; ++tg)
            af[tg] =
                *reinterpret_cast<const bfrag8*>(ypb + (tg * 24 + oc) * 512);
#pragma unroll
        for (int n = 0; n < 3; ++n) {
            bfrag8 bf = *reinterpret_cast<const bfrag8*>(
                wp + ((nt0 + n) * 24 + oc) * 512);
#pragma unroll
            for (int tg = 0; tg < 4; ++tg)
                acc[n][tg] = __builtin_amdgcn_mfma_f32_16x16x32_bf16(
                    af[tg], bf, acc[n][tg], 0, 0, 0);
        }
    }

    // scatter acc into ot[tg][t][ct] (conflict-light: lanes spread banks)
#pragma unroll
    for (int n = 0; n < 3; ++n) {
        const int ct = (w * 3 + n) * 16 + l15;
#pragma unroll
        for (int tg = 0; tg < 4; ++tg)
#pragma unroll
            for (int r = 0; r < 4; ++r) ot[tg][lg * 4 + r][ct] = acc[n][tg][r];
    }
    __syncthreads();

    // wave w: tile tg=w, A-frag order; coalesced b128 stores
    const size_t obase = ((size_t)kb * 128 + ttg0 + w) * 3072;
#pragma unroll
    for (int cc = 0; cc < 6; ++cc) {
        union {
            bfrag8 v8;
            short u[8];
        } A;
#pragma unroll
        for (int j2 = 0; j2 < 8; ++j2)
            A.u[j2] = (short)__bfloat16_as_ushort(
                __float2bfloat16(ot[w][l15][cc * 32 + lg * 8 + j2]));
        *reinterpret_cast<bfrag8*>(
            reinterpret_cast<short*>(ywA) + obase + cc * 512 + (size_t)l * 8) =
            A.v8;
    }
}

// ---------------------------------------------------------------------------
// yb[k,b,t] for all 12 k in one pass over y.
// ---------------------------------------------------------------------------
__global__ __launch_bounds__(256) void k_yb2(const float* __restrict__ y,
                                             const float* __restrict__ bias,
                                             float* __restrict__ yb) {
    const int b = blockIdx.y;
    const int t0 = blockIdx.x * 64;
    const int tid = threadIdx.x;
    const int tl = tid & 63, g = tid >> 6;

    __shared__ float bs[KK][CC];
    __shared__ float pb[4][64][KK];
    for (int i = tid; i < KK * CC; i += 256) bs[i / CC][i % CC] = bias[i];
    __syncthreads();

    float p[KK];
#pragma unroll
    for (int k = 0; k < KK; ++k) p[k] = 0.f;
    const float* yb_ = y + (size_t)b * CC * TT + t0 + tl;
    for (int o = g * 192; o < g * 192 + 192; ++o) {
        float v = yb_[(size_t)o * TT];
#pragma unroll
        for (int k = 0; k < KK; ++k) p[k] += v * bs[k][o];
    }
#pragma unroll
    for (int k = 0; k < KK; ++k) pb[g][tl][k] = p[k];
    __syncthreads();
    for (int i = tid; i < 64 * KK; i += 256) {
        int tt = i / KK, k = i % KK;
        float s = pb[0][tt][k] + pb[1][tt][k] + pb[2][tt][k] + pb[3][tt][k];
        yb[((size_t)k * BB + b) * TT + t0 + tt] = s;
    }
}

// ---------------------------------------------------------------------------
// FUSED attn (R9 structure, proven 144 us / no spill) + s_setprio around the
// score-MFMA cluster (T5: waves between barriers are at diverse phases).
// ---------------------------------------------------------------------------
__global__ __launch_bounds__(512) void k_attn_fused(
    const float* __restrict__ ymask, const float* __restrict__ tmask,
    const float* __restrict__ scale, const __hip_bfloat16* __restrict__ ywA,
    const float* __restrict__ ybws, const __hip_bfloat16* __restrict__ textS,
    const __hip_bfloat16* __restrict__ textC, const float* __restrict__ y,
    const float* __restrict__ ge, float* __restrict__ out) {
    const int i = blockIdx.x;
    const int x = i & 7;
    const int b = x & 3;
    const int tt = (i >> 3) + ((x >> 2) << 6);
    const int t0 = tt * 16;
    const int tid = threadIdx.x;
    const int w = tid >> 6;       // 0..7
    const int l = tid & 63;
    const int l15 = l & 15, lg = l >> 4;
    const int ws0 = w * 128;

    __shared__ float lds_acc[8][8][64][4];   // 64 KB: prob-sum accumulator
    __shared__ uint2 exp_buf[2][8][8][64];   // 64 KB: [p][w][st][l] bf16 exp x4
    __shared__ float yb_s[KK][16];
    __shared__ float sc_s[KK];
    __shared__ __align__(16) float lred[2][2][16][8];  // [kp&1][p][row][w]

    if (tid < 192)
        yb_s[tid >> 4][tid & 15] =
            ybws[(size_t)((tid >> 4) * BB + b) * TT + t0 + (tid & 15)];
    if (tid < KK) sc_s[tid] = scale[tid];
    const f32x4 zero4 = (f32x4){0.f, 0.f, 0.f, 0.f};
#pragma unroll
    for (int st = 0; st < 8; ++st)
        *reinterpret_cast<f32x4*>(&lds_acc[w][st][l][0]) = zero4;
    __syncthreads();

    float tm2r[8];
#pragma unroll
    for (int st = 0; st < 8; ++st) {
        float m = tmask[b * SS + ws0 + st * 16 + l15];
        tm2r[st] = m * m;
    }
    float ymr[4];
#pragma unroll
    for (int r = 0; r < 4; ++r) ymr[r] = ymask[b * TT + t0 + lg * 4 + r];
    const float invs = 0.03608439182435161f;  // 1/sqrt(768)

    const short* ywAs = reinterpret_cast<const short*>(ywA);
    const short* tS = reinterpret_cast<const short*>(textS);
    const short* tSw = tS + (((size_t)b * 64 + w * 8) * 6) * 512 + (size_t)l * 8;
    const size_t headStride = (size_t)BB * 128 * 3072;  // shorts per head

    for (int kp = 0; kp < 6; ++kp) {
        // preload both heads' A-frags: 12 x 16B = 48 VGPR
        bfrag8 af[2][6];
        const size_t ab0 =
            (((size_t)(2 * kp * BB + b) * 128 + tt) * 6) * 512 + (size_t)l * 8;
#pragma unroll
        for (int cc = 0; cc < 6; ++cc) {
            af[0][cc] = *reinterpret_cast<const bfrag8*>(ywAs + ab0 + cc * 512);
            af[1][cc] = *reinterpret_cast<const bfrag8*>(ywAs + ab0 +
                                                         headStride + cc * 512);
        }
        float cfr[2][4], ybk[2][4];
#pragma unroll
        for (int p = 0; p < 2; ++p) {
            const int k = 2 * kp + p;
            const float sk = sc_s[k];
#pragma unroll
            for (int r = 0; r < 4; ++r) {
                ybk[p][r] = yb_s[k][lg * 4 + r];
                cfr[p][r] = sk * ymr[r] * invs;
            }
        }

        float lrow[2][4] = {{0.f, 0.f, 0.f, 0.f}, {0.f, 0.f, 0.f, 0.f}};
#pragma unroll
        for (int st = 0; st < 8; ++st) {
            f32x4 av0 = zero4, av1 = zero4;
            __builtin_amdgcn_s_setprio(1);
#pragma unroll
            for (int cc = 0; cc < 6; ++cc) {
                bfrag8 bf = *reinterpret_cast<const bfrag8*>(
                    tSw + (st * 6 + cc) * 512);
                av0 = __builtin_amdgcn_mfma_f32_16x16x32_bf16(af[0][cc], bf,
                                                              av0, 0, 0, 0);
                av1 = __builtin_amdgcn_mfma_f32_16x16x32_bf16(af[1][cc], bf,
                                                              av1, 0, 0, 0);
            }
            __builtin_amdgcn_s_setprio(0);
            // scale+mask+exp (masked scores exp(0)=1 participate, as ref)
#pragma unroll
            for (int r = 0; r < 4; ++r) {
                float e0 = __expf((av0[r] + ybk[0][r]) * cfr[0][r] * tm2r[st]);
                float e1 = __expf((av1[r] + ybk[1][r]) * cfr[1][r] * tm2r[st]);
                av0[r] = e0;
                av1[r] = e1;
                lrow[0][r] += e0;
                lrow[1][r] += e1;
            }
            exp_buf[0][w][st][l] =
                make_uint2(pk2(av0[0], av0[1]), pk2(av0[2], av0[3]));
            exp_buf[1][w][st][l] =
                make_uint2(pk2(av1[0], av1[1]), pk2(av1[2], av1[3]));
        }

        // block-wide denominator over S=1024
#pragma unroll
        for (int d = 1; d < 16; d <<= 1)
#pragma unroll
            for (int p = 0; p < 2; ++p)
#pragma unroll
                for (int r = 0; r < 4; ++r)
                    lrow[p][r] += __shfl_xor(lrow[p][r], d);
        if (l15 == 0) {
#pragma unroll
            for (int p = 0; p < 2; ++p)
#pragma unroll
                for (int r = 0; r < 4; ++r)
                    lred[kp & 1][p][lg * 4 + r][w] = lrow[p][r];
        }
        __syncthreads();
        float rl[2][4];
#pragma unroll
        for (int p = 0; p < 2; ++p)
#pragma unroll
            for (int r = 0; r < 4; ++r) {
                const float4 v0 = *reinterpret_cast<const float4*>(
                    &lred[kp & 1][p][lg * 4 + r][0]);
                const float4 v1 = *reinterpret_cast<const float4*>(
                    &lred[kp & 1][p][lg * 4 + r][4]);
                rl[p][r] = 1.0f / (v0.x + v0.y + v0.z + v0.w + v1.x + v1.y +
                                   v1.z + v1.w);
            }
        // read exp back, normalize, accumulate (all LDS, wave-private)
#pragma unroll
        for (int st = 0; st < 8; ++st) {
            const uint2 e0 = exp_buf[0][w][st][l];
            const uint2 e1 = exp_buf[1][w][st][l];
            f32x4 cur = *reinterpret_cast<f32x4*>(&lds_acc[w][st][l][0]);
            cur[0] += unpk_lo(e0.x) * rl[0][0] + unpk_lo(e1.x) * rl[1][0];
            cur[1] += unpk_hi(e0.x) * rl[0][1] + unpk_hi(e1.x) * rl[1][1];
            cur[2] += unpk_lo(e0.y) * rl[0][2] + unpk_lo(e1.y) * rl[1][2];
            cur[3] += unpk_hi(e0.y) * rl[0][3] + unpk_hi(e1.y) * rl[1][3];
            *reinterpret_cast<f32x4*>(&lds_acc[w][st][l][0]) = cur;
        }
        // lred[kp&1] safe to reuse at kp+2: reads above precede barrier(kp+1)
    }
    __builtin_amdgcn_s_waitcnt(0);  // own-wave lds_acc writes visible

    // ---------------- context phase ----------------
    const short* tC = reinterpret_cast<const short*>(textC);
    f32x4 cacc[12];
#pragma unroll
    for (int c = 0; c < 12; ++c) cacc[c] = (f32x4){0.f, 0.f, 0.f, 0.f};

#pragma unroll
    for (int sc = 0; sc < 4; ++sc) {
        const int scg = w * 4 + sc;
        union {
            bfrag8 v8;
            unsigned u[4];
        } A;
#pragma unroll
        for (int jp = 0; jp < 4; ++jp) {
            const int s0 = scg * 32 + lg * 8 + jp * 2;
            const int reg0 = s0 >> 7, st0 = (s0 >> 4) & 7;
            const int lo0 = (s0 & 15) | ((l15 >> 2) << 4);
            const int s1 = s0 + 1;
            const int lo1 = (s1 & 15) | ((l15 >> 2) << 4);
            const int ro = l15 & 3;
            float a = lds_acc[reg0][st0][lo0][ro];
            float bb2 = lds_acc[s1 >> 7][(s1 >> 4) & 7][lo1][ro];
            A.u[jp] = pk2(a, bb2);
        }
#pragma unroll
        for (int ctt = 0; ctt < 12; ++ctt) {
            bfrag8 bf = *reinterpret_cast<const bfrag8*>(
                tC + (((size_t)b * 12 + ctt) * 32 + scg) * 512 + (size_t)l * 8);
            cacc[ctt] = __builtin_amdgcn_mfma_f32_16x16x32_bf16(
                A.v8, bf, cacc[ctt], 0, 0, 0);
        }
    }
    __syncthreads();  // all lds_acc reads done before overwrite as 'part'

    float(*part)[16][192] =
        reinterpret_cast<float(*)[16][192]>(&lds_acc[0][0][0][0]);
    if (w < 4) {
#pragma unroll
        for (int ctt = 0; ctt < 12; ++ctt)
#pragma unroll
            for (int r = 0; r < 4; ++r)
                part[w][lg * 4 + r][ctt * 16 + l15] = cacc[ctt][r];
    }
    __syncthreads();
    if (w >= 4) {
#pragma unroll
        for (int ctt = 0; ctt < 12; ++ctt)
#pragma unroll
            for (int r = 0; r < 4; ++r)
                part[w - 4][lg * 4 + r][ctt * 16 + l15] += cacc[ctt][r];
    }
    __syncthreads();

    // epilogue: out[b,c,t0..t0+15] = y + ctx[t][c%192] + ge[b,c]
    const float* yb_ = y + (size_t)b * CC * TT;
    float* ob = out + (size_t)b * CC * TT;
    const float* geb = ge + b * CC;
    for (int c = tid; c < CC; c += 512) {
        const float gev = geb[c];
        const int cm = c % CT;
        const float4* ysrc =
            reinterpret_cast<const float4*>(yb_ + (size_t)c * TT + t0);
        float4* od = reinterpret_cast<float4*>(ob + (size_t)c * TT + t0);
#pragma unroll
        for (int i4 = 0; i4 < 4; ++i4) {
            float4 v = ysrc[i4];
            const int row = i4 * 4;
            v.x += part[0][row + 0][cm] + part[1][row + 0][cm] +
                   part[2][row + 0][cm] + part[3][row + 0][cm] + gev;
            v.y += part[0][row + 1][cm] + part[1][row + 1][cm] +
                   part[2][row + 1][cm] + part[3][row + 1][cm] + gev;
            v.z += part[0][row + 2][cm] + part[1][row + 2][cm] +
                   part[2][row + 2][cm] + part[3][row + 2][cm] + gev;
            v.w += part[0][row + 3][cm] + part[1][row + 3][cm] +
                   part[2][row + 3][cm] + part[3][row + 3][cm] + gev;
            od[i4] = v;
        }
    }
}

// ---------------------------------------------------------------------------
extern "C" void kernel_launch(void* const* d_in, const int* in_sizes, int n_in,
                              void* d_out, int out_size, void* d_ws,
                              size_t ws_size, hipStream_t stream) {
    const float* y      = (const float*)d_in[0];
    const float* ymask  = (const float*)d_in[1];
    const float* text   = (const float*)d_in[2];
    const float* tmask  = (const float*)d_in[3];
    const float* ge     = (const float*)d_in[4];
    const float* W      = (const float*)d_in[5];
    const float* bias   = (const float*)d_in[6];
    const float* scale  = (const float*)d_in[7];
    float* out = (float*)d_out;

    // workspace carve-up (bytes)
    char* ws = (char*)d_ws;
    __hip_bfloat16* ywA   = (__hip_bfloat16*)ws;                 // 37,748,736
    float*          ybws  = (float*)(ws + 37748736);             //    393,216
    __hip_bfloat16* textS = (__hip_bfloat16*)(ws + 38141952);    //  1,572,864
    __hip_bfloat16* textC = (__hip_bfloat16*)(ws + 39714816);    //  1,572,864
    __hip_bfloat16* yP    = (__hip_bfloat16*)(ws + 58064896);    // 12,582,912
    __hip_bfloat16* WP    = (__hip_bfloat16*)(ws + 70647808);    //  3,538,944

    k_pack_all<<<256, 256, 0, stream>>>(text, W, y, textS, textC, WP, yP);
    k_yb2<<<dim3(TT / 64, BB), 256, 0, stream>>>(y, bias, ybws);
    k_yw_mfma<<<1536, 256, 0, stream>>>(yP, WP, ywA);
    k_attn_fused<<<512, 512, 0, stream>>>(ymask, tmask, scale, ywA, ybws,
                                          textS, textC, y, ge, out);
}